// Round 1
// baseline (103.581 us; speedup 1.0000x reference)
//
#include <hip/hip_runtime.h>

// Two-scalar fused loss over 8192x4096 f32 arrays:
//   out[0] = sum( (|y|>=mu) + (0<|y|<mu)*|y|/mu ) / 8192
//   out[1] = sum( (y_echo/22.8 - f)^2 ) / 8192
// Memory-bound streaming reduction: 3 arrays x 134MB read, 8B written.

#define ECHO_SCALE 22.8f
#define N_ROWS 8192.0f

__global__ void init_out_kernel(float* out) {
    if (threadIdx.x < 2) out[threadIdx.x] = 0.0f;
}

__global__ __launch_bounds__(256) void loss_kernel(
    const float4* __restrict__ y,
    const float4* __restrict__ ye,
    const float4* __restrict__ f,
    const float* __restrict__ mu_ptr,
    float* __restrict__ out,
    long long n4)
{
    const float mu = mu_ptr[0];
    const float inv_mu = 1.0f / mu;
    const float inv_echo = 1.0f / ECHO_SCALE;

    float s0 = 0.0f;  // pseudo_l0 partial
    float s1 = 0.0f;  // l2 partial

    long long idx = (long long)blockIdx.x * blockDim.x + threadIdx.x;
    const long long stride = (long long)gridDim.x * blockDim.x;

    for (long long i = idx; i < n4; i += stride) {
        float4 vy = y[i];
        float4 ve = ye[i];
        float4 vf = f[i];

        float ay[4] = { fabsf(vy.x), fabsf(vy.y), fabsf(vy.z), fabsf(vy.w) };
        float ee[4] = { ve.x, ve.y, ve.z, ve.w };
        float ff[4] = { vf.x, vf.y, vf.z, vf.w };

        #pragma unroll
        for (int j = 0; j < 4; ++j) {
            float a = ay[j];
            // hard indicator for a>=mu; linear ramp a/mu for 0<a<mu; 0 at a==0
            float p = (a >= mu) ? 1.0f : ((a > 0.0f) ? a * inv_mu : 0.0f);
            s0 += p;
            float d = ee[j] * inv_echo - ff[j];
            s1 += d * d;
        }
    }

    // wave-64 butterfly reduce
    #pragma unroll
    for (int off = 32; off > 0; off >>= 1) {
        s0 += __shfl_down(s0, off, 64);
        s1 += __shfl_down(s1, off, 64);
    }

    __shared__ float l0[4];
    __shared__ float l1[4];
    const int wave = threadIdx.x >> 6;
    const int lane = threadIdx.x & 63;
    if (lane == 0) { l0[wave] = s0; l1[wave] = s1; }
    __syncthreads();

    if (threadIdx.x == 0) {
        float t0 = 0.0f, t1 = 0.0f;
        #pragma unroll
        for (int w = 0; w < 4; ++w) { t0 += l0[w]; t1 += l1[w]; }
        atomicAdd(&out[0], t0 * (1.0f / N_ROWS));
        atomicAdd(&out[1], t1 * (1.0f / N_ROWS));
    }
}

extern "C" void kernel_launch(void* const* d_in, const int* in_sizes, int n_in,
                              void* d_out, int out_size, void* d_ws, size_t ws_size,
                              hipStream_t stream) {
    const float4* y  = (const float4*)d_in[0];
    const float4* ye = (const float4*)d_in[1];
    const float4* f  = (const float4*)d_in[2];
    const float* mu  = (const float*)d_in[3];
    float* out = (float*)d_out;

    const long long n  = (long long)in_sizes[0];  // 8192*4096, divisible by 4
    const long long n4 = n / 4;

    init_out_kernel<<<1, 64, 0, stream>>>(out);

    const int block = 256;
    int grid = 2048;  // 256 CUs x 8 blocks; grid-stride covers the rest
    long long needed = (n4 + block - 1) / block;
    if (needed < grid) grid = (int)needed;

    loss_kernel<<<grid, block, 0, stream>>>(y, ye, f, mu, out, n4);
}